// Round 2
// baseline (525.974 us; speedup 1.0000x reference)
//
#include <hip/hip_runtime.h>

// Problem constants
#define BN   4
#define CIN  64
#define COUT 64
#define HH   128
#define WW   128
#define HW   16384      // 128*128
#define K2N  9
#define NOFF 18         // 2*K2

// ---------------------------------------------------------------------------
// Weight transposes (run once per launch, tiny):
//   Wt  [k2][cin][cout]  from w_deform[cout][cin][k2]   (36864 floats)
//   Wot [cin][k][c18]    from w_offset[c][cin][k]       (10368 floats)
// ---------------------------------------------------------------------------
__global__ __launch_bounds__(256) void transpose_weights(
    const float* __restrict__ w_def, const float* __restrict__ w_off,
    float* __restrict__ Wt, float* __restrict__ Wot) {
    int idx = blockIdx.x * 256 + threadIdx.x;
    if (idx < K2N * CIN * COUT) {
        int k2 = idx >> 12;
        int r = idx & 4095;
        int cin = r >> 6;
        int cout = r & 63;
        Wt[idx] = w_def[(cout * CIN + cin) * K2N + k2];
    } else {
        int d = idx - K2N * CIN * COUT;
        if (d < CIN * K2N * NOFF) {
            int cin = d / (K2N * NOFF);
            int r = d % (K2N * NOFF);
            int k = r / NOFF;
            int c = r % NOFF;
            Wot[d] = w_off[(c * CIN + cin) * K2N + k];
        }
    }
}

// ---------------------------------------------------------------------------
// Stage 1: 3x3 conv -> 18 offset channels.
// Block = 64 pixels x 4 cin-groups (16 cins each). Each thread keeps all 18
// channel accs; LDS reduce across the 4 groups. 1024 blocks -> 4 blocks/CU.
// ---------------------------------------------------------------------------
__global__ __launch_bounds__(256, 4) void offset_conv(
    const float* __restrict__ x, const float* __restrict__ Wot,
    const float* __restrict__ boff, float* __restrict__ offs) {
    int tid = threadIdx.x;
    int px = tid & 63;
    int grp = tid >> 6;
    int pix = blockIdx.x * 64 + px;
    int b = pix >> 14;
    int hw = pix & (HW - 1);
    int h = hw >> 7;
    int w = hw & 127;

    float acc[NOFF];
#pragma unroll
    for (int c = 0; c < NOFF; c++) acc[c] = 0.f;

    const float* xb = x + ((long)b << 20) + (grp << 18);  // grp*16 cins
#pragma unroll 2
    for (int cin = 0; cin < 16; cin++) {
        const float* xp = xb + (cin << 14);
        float v[9];
#pragma unroll
        for (int kh = 0; kh < 3; kh++) {
            int y = h - 1 + kh;
            bool yok = (unsigned)y < (unsigned)HH;
            int yc = min(max(y, 0), HH - 1);
#pragma unroll
            for (int kw = 0; kw < 3; kw++) {
                int xx = w - 1 + kw;
                bool ok = yok && ((unsigned)xx < (unsigned)WW);
                float val = xp[yc * WW + min(max(xx, 0), WW - 1)];
                v[kh * 3 + kw] = ok ? val : 0.f;
            }
        }
        const float* wr = Wot + (grp * 16 + cin) * (K2N * NOFF);
#pragma unroll
        for (int k = 0; k < 9; k++) {
#pragma unroll
            for (int c = 0; c < NOFF; c++) {
                acc[c] = fmaf(wr[k * NOFF + c], v[k], acc[c]);
            }
        }
    }

    __shared__ float red[64][NOFF + 1];
    for (int g = 1; g < 4; g++) {
        __syncthreads();
        if (grp == g) {
#pragma unroll
            for (int c = 0; c < NOFF; c++) red[px][c] = acc[c];
        }
        __syncthreads();
        if (grp == 0) {
#pragma unroll
            for (int c = 0; c < NOFF; c++) acc[c] += red[px][c];
        }
    }
    if (grp == 0) {
        float* ob = offs + (((long)b * NOFF) << 14) + hw;
#pragma unroll
        for (int c = 0; c < NOFF; c++) ob[c << 14] = acc[c] + boff[c];
    }
}

// ---------------------------------------------------------------------------
// Stage 2: deformable conv. Block = 64 pixels x 4 cin-groups (16 cins each).
// Per (k2): bilinear coords once (validity folded into corner weights).
// Per cin: 4 gathers -> one sample reused across all 64 couts (wave-uniform
// scalar weight loads). LDS reduce across the 4 cin-groups.
// ---------------------------------------------------------------------------
__global__ __launch_bounds__(256, 4) void deform_conv(
    const float* __restrict__ x, const float* __restrict__ offs,
    const float* __restrict__ Wt, const float* __restrict__ bdef,
    float* __restrict__ out) {
    int tid = threadIdx.x;
    int px = tid & 63;
    int grp = tid >> 6;
    int pix = blockIdx.x * 64 + px;
    int b = pix >> 14;
    int hw = pix & (HW - 1);
    int h = hw >> 7;
    int w = hw & 127;

    float acc[COUT];
#pragma unroll
    for (int c = 0; c < COUT; c++) acc[c] = 0.f;

    const float* xb = x + ((long)b << 20) + (grp << 18);  // grp*16 cins
    const float* ob = offs + (((long)b * NOFF) << 14) + hw;

#pragma unroll
    for (int kh = 0; kh < 3; kh++) {
#pragma unroll
        for (int kw = 0; kw < 3; kw++) {
            int k2 = kh * 3 + kw;
            float dy = ob[(2 * k2) << 14];
            float dx = ob[(2 * k2 + 1) << 14];
            float py = (float)(h - 1 + kh) + dy;
            float px_ = (float)(w - 1 + kw) + dx;
            float y0f = floorf(py), x0f = floorf(px_);
            int y0 = (int)y0f, x0 = (int)x0f;
            float wy1 = py - y0f, wy0 = 1.f - wy1;
            float wx1 = px_ - x0f, wx0 = 1.f - wx1;
            int y1 = y0 + 1, x1 = x0 + 1;
            bool vy0 = (unsigned)y0 < (unsigned)HH, vy1 = (unsigned)y1 < (unsigned)HH;
            bool vx0 = (unsigned)x0 < (unsigned)WW, vx1 = (unsigned)x1 < (unsigned)WW;
            float w00 = (vy0 && vx0) ? wy0 * wx0 : 0.f;
            float w01 = (vy0 && vx1) ? wy0 * wx1 : 0.f;
            float w10 = (vy1 && vx0) ? wy1 * wx0 : 0.f;
            float w11 = (vy1 && vx1) ? wy1 * wx1 : 0.f;
            int y0c = min(max(y0, 0), HH - 1), y1c = min(max(y1, 0), HH - 1);
            int x0c = min(max(x0, 0), WW - 1), x1c = min(max(x1, 0), WW - 1);
            int i00 = y0c * WW + x0c, i01 = y0c * WW + x1c;
            int i10 = y1c * WW + x0c, i11 = y1c * WW + x1c;

            const float* wk = Wt + (k2 << 12) + (grp << 10);  // [cin16][64]
#pragma unroll 2
            for (int cin = 0; cin < 16; cin++) {
                const float* xp = xb + (cin << 14);
                float s = w00 * xp[i00] + w01 * xp[i01] + w10 * xp[i10] + w11 * xp[i11];
                const float* wr = wk + (cin << 6);
#pragma unroll
                for (int c = 0; c < COUT; c++) {
                    acc[c] = fmaf(wr[c], s, acc[c]);
                }
            }
        }
    }

    // Reduce the 4 cin-group partials (16.6 KB LDS, +1 pad: conflict-free).
    __shared__ float red[64][COUT + 1];
    for (int g = 1; g < 4; g++) {
        __syncthreads();
        if (grp == g) {
#pragma unroll
            for (int c = 0; c < COUT; c++) red[px][c] = acc[c];
        }
        __syncthreads();
        if (grp == 0) {
#pragma unroll
            for (int c = 0; c < COUT; c++) acc[c] += red[px][c];
        }
    }
    if (grp == 0) {
        float* op = out + (((long)b * COUT) << 14) + hw;
#pragma unroll
        for (int c = 0; c < COUT; c++) op[c << 14] = acc[c] + bdef[c];
    }
}

// ---------------------------------------------------------------------------
extern "C" void kernel_launch(void* const* d_in, const int* in_sizes, int n_in,
                              void* d_out, int out_size, void* d_ws, size_t ws_size,
                              hipStream_t stream) {
    const float* x     = (const float*)d_in[0];  // (4,64,128,128)
    const float* w_off = (const float*)d_in[1];  // (18,64,3,3)
    const float* b_off = (const float*)d_in[2];  // (18,)
    const float* w_def = (const float*)d_in[3];  // (64,64,3,3)
    const float* b_def = (const float*)d_in[4];  // (64,)
    float* out = (float*)d_out;                  // (4,64,128,128)

    float* offs = (float*)d_ws;                       // 4*18*16384
    float* Wt   = offs + (long)BN * NOFF * HW;        // 36864
    float* Wot  = Wt + K2N * CIN * COUT;              // 10368

    const int n_t = K2N * CIN * COUT + CIN * K2N * NOFF;  // 47232
    hipLaunchKernelGGL(transpose_weights, dim3((n_t + 255) / 256), dim3(256), 0, stream,
                       w_def, w_off, Wt, Wot);

    const int n_blk = BN * HW / 64;  // 1024 blocks: 64 px x 4 cin-groups each
    hipLaunchKernelGGL(offset_conv, dim3(n_blk), dim3(256), 0, stream,
                       x, Wot, b_off, offs);
    hipLaunchKernelGGL(deform_conv, dim3(n_blk), dim3(256), 0, stream,
                       x, offs, Wt, b_def, out);
}

// Round 3
// 458.759 us; speedup vs baseline: 1.1465x; 1.1465x over previous
//
#include <hip/hip_runtime.h>

// Problem constants
#define BN   4
#define CIN  64
#define COUT 64
#define HH   128
#define WW   128
#define HW   16384      // 128*128
#define K2N  9
#define NOFF 18         // 2*K2

// bf16 helpers (round-to-nearest-even; inputs finite)
__device__ __forceinline__ unsigned short f2bf(float f) {
    unsigned int b = __float_as_uint(f);
    b += 0x7fffu + ((b >> 16) & 1u);
    return (unsigned short)(b >> 16);
}
__device__ __forceinline__ float bf2f(unsigned short u) {
    return __uint_as_float(((unsigned int)u) << 16);
}

// ---------------------------------------------------------------------------
// Weight transposes (tiny):
//   Wt  [k2][cin][cout] from w_deform[cout][cin][k2]
//   Wot [cin][k][c18]   from w_offset[c][cin][k]
// Contiguous-in-cout so the hot kernels read weights wave-uniformly (s_load).
// ---------------------------------------------------------------------------
__global__ __launch_bounds__(256) void transpose_weights(
    const float* __restrict__ w_def, const float* __restrict__ w_off,
    float* __restrict__ Wt, float* __restrict__ Wot) {
    int idx = blockIdx.x * 256 + threadIdx.x;
    if (idx < K2N * CIN * COUT) {
        int k2 = idx >> 12;
        int r = idx & 4095;
        int cin = r >> 6;
        int cout = r & 63;
        Wt[idx] = w_def[(cout * CIN + cin) * K2N + k2];
    } else {
        int d = idx - K2N * CIN * COUT;
        if (d < CIN * K2N * NOFF) {
            int cin = d / (K2N * NOFF);
            int r = d % (K2N * NOFF);
            int k = r / NOFF;
            int c = r % NOFF;
            Wot[d] = w_off[(c * CIN + cin) * K2N + k];
        }
    }
}

// ---------------------------------------------------------------------------
// Stage 1: 3x3 conv -> 18 offset channels.
// Block = 8x8 px tile. All 64 cin planes of the 10x10 halo window staged in
// LDS as bf16 (12.8 KB). 4 waves split cin 4x16; LDS reduce. Grid 1024 blocks
// -> 4 blocks/CU, 4 waves/SIMD. Zero-padded tile handles image borders.
// ---------------------------------------------------------------------------
#define OT_H 10
#define OT_N 100
__global__ __launch_bounds__(256, 4) void offset_conv(
    const float* __restrict__ x, const float* __restrict__ Wot,
    const float* __restrict__ boff, float* __restrict__ offs) {
    int tid = threadIdx.x;
    int lane = tid & 63, grp = tid >> 6;
    int blk = blockIdx.x;
    int b = blk >> 8;
    int t = blk & 255;
    int h0 = (t >> 4) << 3, w0 = (t & 15) << 3;

    __shared__ unsigned short tile[CIN * OT_N];  // 12800 B
    const float* xb = x + ((long)b << 20);
    for (int e = tid; e < CIN * OT_N; e += 256) {
        int p = e / OT_N;
        int r = e - p * OT_N;
        int ty = r / OT_H, tx = r - ty * OT_H;
        int y = h0 - 1 + ty, xx = w0 - 1 + tx;
        float v = 0.f;
        if ((unsigned)y < (unsigned)HH && (unsigned)xx < (unsigned)WW)
            v = xb[(p << 14) + (y << 7) + xx];
        tile[e] = f2bf(v);
    }
    __syncthreads();

    int lh = lane >> 3, lw = lane & 7;
    float acc[NOFF];
#pragma unroll
    for (int c = 0; c < NOFF; c++) acc[c] = 0.f;

    const unsigned short* tg = tile + (grp << 4) * OT_N;  // this wave's 16 planes
    for (int cin = 0; cin < 16; ++cin) {
        const unsigned short* tp = tg + cin * OT_N + lh * OT_H + lw;
        float v[9];
#pragma unroll
        for (int kh = 0; kh < 3; kh++)
#pragma unroll
            for (int kw = 0; kw < 3; kw++)
                v[kh * 3 + kw] = bf2f(tp[kh * OT_H + kw]);
        const float* wr = Wot + ((grp << 4) + cin) * (K2N * NOFF);
#pragma unroll
        for (int k = 0; k < 9; k++)
#pragma unroll
            for (int c = 0; c < NOFF; c++)
                acc[c] = fmaf(wr[k * NOFF + c], v[k], acc[c]);
    }

    // Reduce 4 cin-group partials. red aliases tile (4864 B <= 12800 B);
    // first barrier of round 1 guarantees all tile reads are done.
    float (*red)[NOFF + 1] = (float(*)[NOFF + 1])tile;
    for (int g = 1; g < 4; g++) {
        __syncthreads();
        if (grp == g) {
#pragma unroll
            for (int c = 0; c < NOFF; c++) red[lane][c] = acc[c];
        }
        __syncthreads();
        if (grp == 0) {
#pragma unroll
            for (int c = 0; c < NOFF; c++) acc[c] += red[lane][c];
        }
    }
    if (grp == 0) {
        int hw = ((h0 + lh) << 7) + w0 + lw;
        float* ob = offs + (((long)b * NOFF) << 14) + hw;
#pragma unroll
        for (int c = 0; c < NOFF; c++) ob[c << 14] = acc[c] + boff[c];
    }
}

// ---------------------------------------------------------------------------
// Stage 2: deformable conv. Block = 8x8 px tile; all 64 cin planes of the
// 15x15 halo window (taps +-1, offsets +-2: >8 sigma) staged in LDS as bf16
// (28.8 KB -> 4 blocks/CU). 4 waves split cin 4x16, each samples all 9 taps
// from LDS (thrash-immune), acc[64] per thread, LDS reduce. Out-of-tile
// samples (essentially never) corrected exactly via a global-memory pass
// under __any() (execz-skipped when not taken). Tile holds zeros at
// out-of-image positions, so the fast path needs no validity masking.
// ---------------------------------------------------------------------------
#define DT_H 15
#define DT_N 225
__global__ __launch_bounds__(256, 4) void deform_conv(
    const float* __restrict__ x, const float* __restrict__ offs,
    const float* __restrict__ Wt, const float* __restrict__ bdef,
    float* __restrict__ out) {
    int tid = threadIdx.x;
    int lane = tid & 63, grp = tid >> 6;
    int blk = blockIdx.x;
    int b = blk >> 8;
    int t = blk & 255;
    int h0 = (t >> 4) << 3, w0 = (t & 15) << 3;
    int ty0 = h0 - 3, tx0 = w0 - 3;

    __shared__ unsigned short tile[CIN * DT_N];  // 28800 B
    const float* xb = x + ((long)b << 20);
    for (int e = tid; e < CIN * DT_N; e += 256) {
        int p = e / DT_N;
        int r = e - p * DT_N;
        int ty = r / DT_H, tx = r - ty * DT_H;
        int y = ty0 + ty, xx = tx0 + tx;
        float v = 0.f;
        if ((unsigned)y < (unsigned)HH && (unsigned)xx < (unsigned)WW)
            v = xb[(p << 14) + (y << 7) + xx];
        tile[e] = f2bf(v);
    }
    __syncthreads();

    int lh = lane >> 3, lw = lane & 7;
    int h = h0 + lh, w = w0 + lw;
    int hw = (h << 7) + w;
    const float* ob = offs + (((long)b * NOFF) << 14) + hw;

    float acc[COUT];
#pragma unroll
    for (int c = 0; c < COUT; c++) acc[c] = 0.f;

    const unsigned short* tg = tile + (grp << 4) * DT_N;  // this wave's 16 planes

    for (int k2 = 0; k2 < K2N; k2++) {
        int kh = k2 / 3;
        int kw = k2 - kh * 3;
        float dy = ob[k2 << 15];              // channel 2*k2
        float dx = ob[(2 * k2 + 1) << 14];    // channel 2*k2+1
        float py = (float)(h - 1 + kh) + dy;
        float px_ = (float)(w - 1 + kw) + dx;
        float y0f = floorf(py), x0f = floorf(px_);
        int y0 = (int)y0f, x0 = (int)x0f;
        float wy1 = py - y0f, wy0 = 1.f - wy1;
        float wx1 = px_ - x0f, wx0 = 1.f - wx1;
        float w00 = wy0 * wx0, w01 = wy0 * wx1;
        float w10 = wy1 * wx0, w11 = wy1 * wx1;

        int by = y0 - ty0, bx = x0 - tx0;     // corner in tile coords
        bool oob = ((unsigned)by > 13u) | ((unsigned)bx > 13u);
        int byc = min(max(by, 0), 13), bxc = min(max(bx, 0), 13);
        int base = byc * DT_H + bxc;

        const float* wk = Wt + (k2 << 12) + (grp << 10);
        for (int cin = 0; cin < 16; ++cin) {
            const unsigned short* tp = tg + cin * DT_N + base;
            float s = w00 * bf2f(tp[0]) + w01 * bf2f(tp[1])
                    + w10 * bf2f(tp[DT_H]) + w11 * bf2f(tp[DT_H + 1]);
            const float* wr = wk + (cin << 6);
#pragma unroll
            for (int c = 0; c < COUT; c++)
                acc[c] = fmaf(wr[c], s, acc[c]);
        }

        if (__any(oob)) {  // exact correction for out-of-tile samples (rare)
            int y1 = y0 + 1, x1 = x0 + 1;
            bool vy0 = (unsigned)y0 < (unsigned)HH, vy1 = (unsigned)y1 < (unsigned)HH;
            bool vx0 = (unsigned)x0 < (unsigned)WW, vx1 = (unsigned)x1 < (unsigned)WW;
            float m00 = (vy0 && vx0) ? w00 : 0.f;
            float m01 = (vy0 && vx1) ? w01 : 0.f;
            float m10 = (vy1 && vx0) ? w10 : 0.f;
            float m11 = (vy1 && vx1) ? w11 : 0.f;
            int y0c = min(max(y0, 0), HH - 1), y1c = min(max(y1, 0), HH - 1);
            int x0c = min(max(x0, 0), WW - 1), x1c = min(max(x1, 0), WW - 1);
            int i00 = y0c * WW + x0c, i01 = y0c * WW + x1c;
            int i10 = y1c * WW + x0c, i11 = y1c * WW + x1c;
            for (int cin = 0; cin < 16; ++cin) {
                const unsigned short* tp = tg + cin * DT_N + base;
                float sl = w00 * bf2f(tp[0]) + w01 * bf2f(tp[1])
                         + w10 * bf2f(tp[DT_H]) + w11 * bf2f(tp[DT_H + 1]);
                const float* xp = xb + (((grp << 4) + cin) << 14);
                float sg = m00 * xp[i00] + m01 * xp[i01] + m10 * xp[i10] + m11 * xp[i11];
                float d = oob ? (sg - sl) : 0.f;
                const float* wr = wk + (cin << 6);
#pragma unroll
                for (int c = 0; c < COUT; c++)
                    acc[c] = fmaf(wr[c], d, acc[c]);
            }
        }
    }

    // Reduce 4 cin-group partials. red aliases tile (16640 B <= 28800 B).
    float (*red)[COUT + 1] = (float(*)[COUT + 1])tile;
    for (int g = 1; g < 4; g++) {
        __syncthreads();
        if (grp == g) {
#pragma unroll
            for (int c = 0; c < COUT; c++) red[lane][c] = acc[c];
        }
        __syncthreads();
        if (grp == 0) {
#pragma unroll
            for (int c = 0; c < COUT; c++) acc[c] += red[lane][c];
        }
    }
    if (grp == 0) {
        float* op = out + (((long)b * COUT) << 14) + hw;
#pragma unroll
        for (int c = 0; c < COUT; c++) op[c << 14] = acc[c] + bdef[c];
    }
}

// ---------------------------------------------------------------------------
extern "C" void kernel_launch(void* const* d_in, const int* in_sizes, int n_in,
                              void* d_out, int out_size, void* d_ws, size_t ws_size,
                              hipStream_t stream) {
    const float* x     = (const float*)d_in[0];  // (4,64,128,128)
    const float* w_off = (const float*)d_in[1];  // (18,64,3,3)
    const float* b_off = (const float*)d_in[2];  // (18,)
    const float* w_def = (const float*)d_in[3];  // (64,64,3,3)
    const float* b_def = (const float*)d_in[4];  // (64,)
    float* out = (float*)d_out;                  // (4,64,128,128)

    float* offs = (float*)d_ws;                       // 4*18*16384
    float* Wt   = offs + (long)BN * NOFF * HW;        // 36864
    float* Wot  = Wt + K2N * CIN * COUT;              // 10368

    const int n_t = K2N * CIN * COUT + CIN * K2N * NOFF;  // 47232
    hipLaunchKernelGGL(transpose_weights, dim3((n_t + 255) / 256), dim3(256), 0, stream,
                       w_def, w_off, Wt, Wot);

    const int n_blk = BN * HW / 64;  // 1024 blocks: one 8x8 px tile each
    hipLaunchKernelGGL(offset_conv, dim3(n_blk), dim3(256), 0, stream,
                       x, Wot, b_off, offs);
    hipLaunchKernelGGL(deform_conv, dim3(n_blk), dim3(256), 0, stream,
                       x, offs, Wt, b_def, out);
}

// Round 4
// 262.199 us; speedup vs baseline: 2.0060x; 1.7497x over previous
//
#include <hip/hip_runtime.h>

// Problem constants
#define BN   4
#define CIN  64
#define COUT 64
#define HH   128
#define WW   128
#define HW   16384      // 128*128
#define K2N  9
#define NOFF 18         // 2*K2

// bf16 helpers (round-to-nearest-even; inputs finite)
__device__ __forceinline__ unsigned short f2bf(float f) {
    unsigned int b = __float_as_uint(f);
    b += 0x7fffu + ((b >> 16) & 1u);
    return (unsigned short)(b >> 16);
}
__device__ __forceinline__ float bf2f(unsigned short u) {
    return __uint_as_float(((unsigned int)u) << 16);
}

// ---------------------------------------------------------------------------
// Weight transposes (tiny):
//   Wt  [k2][cin][cout] from w_deform[cout][cin][k2]
//   Wot [cin][k][c18]   from w_offset[c][cin][k]
// ---------------------------------------------------------------------------
__global__ __launch_bounds__(256) void transpose_weights(
    const float* __restrict__ w_def, const float* __restrict__ w_off,
    float* __restrict__ Wt, float* __restrict__ Wot) {
    int idx = blockIdx.x * 256 + threadIdx.x;
    if (idx < K2N * CIN * COUT) {
        int k2 = idx >> 12;
        int r = idx & 4095;
        int cin = r >> 6;
        int cout = r & 63;
        Wt[idx] = w_def[(cout * CIN + cin) * K2N + k2];
    } else {
        int d = idx - K2N * CIN * COUT;
        if (d < CIN * K2N * NOFF) {
            int cin = d / (K2N * NOFF);
            int r = d % (K2N * NOFF);
            int k = r / NOFF;
            int c = r % NOFF;
            Wot[d] = w_off[(c * CIN + cin) * K2N + k];
        }
    }
}

// ---------------------------------------------------------------------------
// Stage 1: 3x3 conv -> 18 offset channels.
// Block = 8x8 px tile; 64 cin planes of the 10x10 halo in LDS as bf16.
// 4 waves split cin 4x16 (grpu = readfirstlane(grp) keeps weight addresses
// provably wave-uniform -> s_load, scalar pipe). LDS reduce.
// ---------------------------------------------------------------------------
#define OT_H 10
#define OT_N 100
__global__ __launch_bounds__(256, 4) void offset_conv(
    const float* __restrict__ x, const float* __restrict__ Wot,
    const float* __restrict__ boff, float* __restrict__ offs) {
    int tid = threadIdx.x;
    int lane = tid & 63, grp = tid >> 6;
    int grpu = __builtin_amdgcn_readfirstlane(grp);  // wave-uniform in SGPR
    int blk = blockIdx.x;
    int b = blk >> 8;
    int t = blk & 255;
    int h0 = (t >> 4) << 3, w0 = (t & 15) << 3;

    __shared__ unsigned short tile[CIN * OT_N];  // 12800 B
    const float* xb = x + ((long)b << 20);
    for (int e = tid; e < CIN * OT_N; e += 256) {
        int p = e / OT_N;
        int r = e - p * OT_N;
        int ty = r / OT_H, tx = r - ty * OT_H;
        int y = h0 - 1 + ty, xx = w0 - 1 + tx;
        float v = 0.f;
        if ((unsigned)y < (unsigned)HH && (unsigned)xx < (unsigned)WW)
            v = xb[(p << 14) + (y << 7) + xx];
        tile[e] = f2bf(v);
    }
    __syncthreads();

    int lh = lane >> 3, lw = lane & 7;
    float acc[NOFF];
#pragma unroll
    for (int c = 0; c < NOFF; c++) acc[c] = 0.f;

    const unsigned short* tg = tile + (grpu << 4) * OT_N;  // this wave's 16 planes
#pragma unroll 2
    for (int cin = 0; cin < 16; ++cin) {
        const unsigned short* tp = tg + cin * OT_N + lh * OT_H + lw;
        float v[9];
#pragma unroll
        for (int kh = 0; kh < 3; kh++)
#pragma unroll
            for (int kw = 0; kw < 3; kw++)
                v[kh * 3 + kw] = bf2f(tp[kh * OT_H + kw]);
        const float* wr = Wot + ((grpu << 4) + cin) * (K2N * NOFF);  // uniform
#pragma unroll
        for (int k = 0; k < 9; k++)
#pragma unroll
            for (int c = 0; c < NOFF; c++)
                acc[c] = fmaf(wr[k * NOFF + c], v[k], acc[c]);
    }

    // Reduce 4 cin-group partials (red aliases tile; barrier protects reads).
    float (*red)[NOFF + 1] = (float(*)[NOFF + 1])tile;
    for (int g = 1; g < 4; g++) {
        __syncthreads();
        if (grp == g) {
#pragma unroll
            for (int c = 0; c < NOFF; c++) red[lane][c] = acc[c];
        }
        __syncthreads();
        if (grp == 0) {
#pragma unroll
            for (int c = 0; c < NOFF; c++) acc[c] += red[lane][c];
        }
    }
    if (grp == 0) {
        int hw = ((h0 + lh) << 7) + w0 + lw;
        float* ob = offs + (((long)b * NOFF) << 14) + hw;
#pragma unroll
        for (int c = 0; c < NOFF; c++) ob[c << 14] = acc[c] + boff[c];
    }
}

// ---------------------------------------------------------------------------
// Stage 2: deformable conv. Block = 8x8 px tile; 64 cin planes of the 15x15
// halo in LDS as bf16 (28.8 KB -> 4 blocks/CU). 4 waves split cin 4x16
// (grpu keeps weight addresses wave-uniform -> s_load). cin loop unrolled 4x
// so ds_read latency batches. Out-of-tile samples corrected exactly via
// global memory under __any() (execz-skipped normally). Tile zeros at
// out-of-image positions make fast-path validity masking free.
// ---------------------------------------------------------------------------
#define DT_H 15
#define DT_N 225
__global__ __launch_bounds__(256, 4) void deform_conv(
    const float* __restrict__ x, const float* __restrict__ offs,
    const float* __restrict__ Wt, const float* __restrict__ bdef,
    float* __restrict__ out) {
    int tid = threadIdx.x;
    int lane = tid & 63, grp = tid >> 6;
    int grpu = __builtin_amdgcn_readfirstlane(grp);  // wave-uniform in SGPR
    int blk = blockIdx.x;
    int b = blk >> 8;
    int t = blk & 255;
    int h0 = (t >> 4) << 3, w0 = (t & 15) << 3;
    int ty0 = h0 - 3, tx0 = w0 - 3;

    __shared__ unsigned short tile[CIN * DT_N];  // 28800 B
    const float* xb = x + ((long)b << 20);
    for (int e = tid; e < CIN * DT_N; e += 256) {
        int p = e / DT_N;
        int r = e - p * DT_N;
        int ty = r / DT_H, tx = r - ty * DT_H;
        int y = ty0 + ty, xx = tx0 + tx;
        float v = 0.f;
        if ((unsigned)y < (unsigned)HH && (unsigned)xx < (unsigned)WW)
            v = xb[(p << 14) + (y << 7) + xx];
        tile[e] = f2bf(v);
    }
    __syncthreads();

    int lh = lane >> 3, lw = lane & 7;
    int h = h0 + lh, w = w0 + lw;
    int hw = (h << 7) + w;
    const float* ob = offs + (((long)b * NOFF) << 14) + hw;

    float acc[COUT];
#pragma unroll
    for (int c = 0; c < COUT; c++) acc[c] = 0.f;

    const unsigned short* tg = tile + (grpu << 4) * DT_N;  // this wave's 16 planes

    for (int k2 = 0; k2 < K2N; k2++) {
        int kh = k2 / 3;
        int kw = k2 - kh * 3;
        float dy = ob[k2 << 15];              // channel 2*k2
        float dx = ob[(2 * k2 + 1) << 14];    // channel 2*k2+1
        float py = (float)(h - 1 + kh) + dy;
        float px_ = (float)(w - 1 + kw) + dx;
        float y0f = floorf(py), x0f = floorf(px_);
        int y0 = (int)y0f, x0 = (int)x0f;
        float wy1 = py - y0f, wy0 = 1.f - wy1;
        float wx1 = px_ - x0f, wx0 = 1.f - wx1;
        float w00 = wy0 * wx0, w01 = wy0 * wx1;
        float w10 = wy1 * wx0, w11 = wy1 * wx1;

        int by = y0 - ty0, bx = x0 - tx0;     // corner in tile coords
        bool oob = ((unsigned)by > 13u) | ((unsigned)bx > 13u);
        int byc = min(max(by, 0), 13), bxc = min(max(bx, 0), 13);
        int base = byc * DT_H + bxc;

        const float* wk = Wt + (k2 << 12) + (grpu << 10);  // uniform slab base
#pragma unroll 4
        for (int cin = 0; cin < 16; ++cin) {
            const unsigned short* tp = tg + cin * DT_N + base;
            float s = w00 * bf2f(tp[0]) + w01 * bf2f(tp[1])
                    + w10 * bf2f(tp[DT_H]) + w11 * bf2f(tp[DT_H + 1]);
            const float* wr = wk + (cin << 6);  // uniform -> s_load
#pragma unroll
            for (int c = 0; c < COUT; c++)
                acc[c] = fmaf(wr[c], s, acc[c]);
        }

        if (__any(oob)) {  // exact correction for out-of-tile samples (rare)
            int y1 = y0 + 1, x1 = x0 + 1;
            bool vy0 = (unsigned)y0 < (unsigned)HH, vy1 = (unsigned)y1 < (unsigned)HH;
            bool vx0 = (unsigned)x0 < (unsigned)WW, vx1 = (unsigned)x1 < (unsigned)WW;
            float m00 = (vy0 && vx0) ? w00 : 0.f;
            float m01 = (vy0 && vx1) ? w01 : 0.f;
            float m10 = (vy1 && vx0) ? w10 : 0.f;
            float m11 = (vy1 && vx1) ? w11 : 0.f;
            int y0c = min(max(y0, 0), HH - 1), y1c = min(max(y1, 0), HH - 1);
            int x0c = min(max(x0, 0), WW - 1), x1c = min(max(x1, 0), WW - 1);
            int i00 = y0c * WW + x0c, i01 = y0c * WW + x1c;
            int i10 = y1c * WW + x0c, i11 = y1c * WW + x1c;
            for (int cin = 0; cin < 16; ++cin) {
                const unsigned short* tp = tg + cin * DT_N + base;
                float sl = w00 * bf2f(tp[0]) + w01 * bf2f(tp[1])
                         + w10 * bf2f(tp[DT_H]) + w11 * bf2f(tp[DT_H + 1]);
                const float* xp = xb + (((grpu << 4) + cin) << 14);
                float sg = m00 * xp[i00] + m01 * xp[i01] + m10 * xp[i10] + m11 * xp[i11];
                float d = oob ? (sg - sl) : 0.f;
                const float* wr = wk + (cin << 6);
#pragma unroll
                for (int c = 0; c < COUT; c++)
                    acc[c] = fmaf(wr[c], d, acc[c]);
            }
        }
    }

    // Reduce 4 cin-group partials (red aliases tile; barrier protects reads).
    float (*red)[COUT + 1] = (float(*)[COUT + 1])tile;
    for (int g = 1; g < 4; g++) {
        __syncthreads();
        if (grp == g) {
#pragma unroll
            for (int c = 0; c < COUT; c++) red[lane][c] = acc[c];
        }
        __syncthreads();
        if (grp == 0) {
#pragma unroll
            for (int c = 0; c < COUT; c++) acc[c] += red[lane][c];
        }
    }
    if (grp == 0) {
        float* op = out + (((long)b * COUT) << 14) + hw;
#pragma unroll
        for (int c = 0; c < COUT; c++) op[c << 14] = acc[c] + bdef[c];
    }
}

// ---------------------------------------------------------------------------
extern "C" void kernel_launch(void* const* d_in, const int* in_sizes, int n_in,
                              void* d_out, int out_size, void* d_ws, size_t ws_size,
                              hipStream_t stream) {
    const float* x     = (const float*)d_in[0];  // (4,64,128,128)
    const float* w_off = (const float*)d_in[1];  // (18,64,3,3)
    const float* b_off = (const float*)d_in[2];  // (18,)
    const float* w_def = (const float*)d_in[3];  // (64,64,3,3)
    const float* b_def = (const float*)d_in[4];  // (64,)
    float* out = (float*)d_out;                  // (4,64,128,128)

    float* offs = (float*)d_ws;                       // 4*18*16384
    float* Wt   = offs + (long)BN * NOFF * HW;        // 36864
    float* Wot  = Wt + K2N * CIN * COUT;              // 10368

    const int n_t = K2N * CIN * COUT + CIN * K2N * NOFF;  // 47232
    hipLaunchKernelGGL(transpose_weights, dim3((n_t + 255) / 256), dim3(256), 0, stream,
                       w_def, w_off, Wt, Wot);

    const int n_blk = BN * HW / 64;  // 1024 blocks: one 8x8 px tile each
    hipLaunchKernelGGL(offset_conv, dim3(n_blk), dim3(256), 0, stream,
                       x, Wot, b_off, offs);
    hipLaunchKernelGGL(deform_conv, dim3(n_blk), dim3(256), 0, stream,
                       x, offs, Wt, b_def, out);
}

// Round 5
// 115.969 us; speedup vs baseline: 4.5355x; 2.2609x over previous
//
#include <hip/hip_runtime.h>

// Problem: B=4, CIN=COUT=64, H=W=128, 3x3 deformable conv, fp32 in/out.
// Strategy: one fused MFMA kernel per 8x8-pixel tile (1024 blocks):
//   stage x halo (15x15x64) in LDS bf16 [pos][cin] -> stage-1 offset conv via
//   mfma_f32_16x16x32_bf16 (N=18 pad 32) -> bilinear-sample A-fragments from
//   LDS -> stage-2 GEMM D[64px][64cout] via MFMA -> LDS transpose -> store.
// Weights pre-packed into per-lane B-fragment order by a tiny prologue kernel.

typedef __attribute__((ext_vector_type(8))) short short8x;
typedef __attribute__((ext_vector_type(4))) float float4x;
typedef unsigned short ushort;
typedef unsigned int uint;

__device__ __forceinline__ ushort f2bf(float f) {
    uint b = __float_as_uint(f);
    b += 0x7fffu + ((b >> 16) & 1u);
    return (ushort)(b >> 16);
}
__device__ __forceinline__ float bf2f(ushort u) {
    return __uint_as_float(((uint)u) << 16);
}

// ---------------------------------------------------------------------------
// Prologue: pack weights into MFMA B-fragment order (bf16).
//  Bd [kk(18)][nt(4)][lane(64)][i(8)]: n = nt*16+(lane&15),
//     k = kk*32 + (lane>>4)*8 + i -> k2 = kk>>1, cin = (kk&1)*32+(lane>>4)*8+i
//  Bo [kk(18)][nt(2)][lane][i]: same, n>=18 zero-padded.
// Consistent-permutation: A is built with the identical k mapping, so any
// slot->k bijection cancels; C/D mapping is the m89-verified one.
// ---------------------------------------------------------------------------
__global__ __launch_bounds__(256) void pack_weights(
    const float* __restrict__ w_def, const float* __restrict__ w_off,
    ushort* __restrict__ Bd, ushort* __restrict__ Bo) {
    int idx = blockIdx.x * 256 + threadIdx.x;
    if (idx < 36864) {
        int i = idx & 7;
        int lane = (idx >> 3) & 63;
        int nt = (idx >> 9) & 3;
        int kk = idx >> 11;
        int n = (nt << 4) + (lane & 15);
        int k2 = kk >> 1;
        int cin = ((kk & 1) << 5) + ((lane >> 4) << 3) + i;
        Bd[idx] = f2bf(w_def[(n * 64 + cin) * 9 + k2]);
    } else if (idx < 36864 + 18432) {
        int d = idx - 36864;
        int i = d & 7;
        int lane = (d >> 3) & 63;
        int nt = (d >> 9) & 1;
        int kk = d >> 10;
        int n = (nt << 4) + (lane & 15);
        int k2 = kk >> 1;
        int cin = ((kk & 1) << 5) + ((lane >> 4) << 3) + i;
        Bo[d] = (n < 18) ? f2bf(w_off[(n * 64 + cin) * 9 + k2]) : (ushort)0;
    }
}

// ---------------------------------------------------------------------------
// Fused kernel. Block = 8x8 pixel tile, 256 threads = 4 waves (M-split:
// wave w owns pixels 16w..16w+15).
// ---------------------------------------------------------------------------
__global__ __launch_bounds__(256, 4) void dcn_fused(
    const float* __restrict__ x, const ushort* __restrict__ Bd,
    const ushort* __restrict__ Bo, const float* __restrict__ boff,
    const float* __restrict__ bdef, float* __restrict__ out) {

    int tid = threadIdx.x;
    int lane = tid & 63, wv = tid >> 6;
    int blk = blockIdx.x;
    int b = blk >> 8, t = blk & 255;
    int h0 = (t >> 4) << 3, w0 = (t & 15) << 3;

    // tile[pos(225, stride 72)][cin(64)+pad8] bf16: 32400 B. pixel stride
    // 144 B = 36 dw = 4 banks mod 32 -> consecutive positions conflict-light.
    __shared__ __align__(16) ushort tile[225 * 72];
    __shared__ float offl[64 * 18];  // [px][ch] offsets, 4608 B

    const float* xb = x + ((long)b << 20);

    // ---- stage halo: thread = one pos, reads 64 planes (coalesced across
    // lanes per plane), packs bf16 pairs, 8x ds_write_b128 (2-way = free).
    if (tid < 225) {
        int ty = tid / 15, tx = tid - ty * 15;
        int y = h0 - 3 + ty, xx = w0 - 3 + tx;
        bool valid = ((unsigned)y < 128u) & ((unsigned)xx < 128u);
        int yc = min(max(y, 0), 127), xc = min(max(xx, 0), 127);
        const float* gp = xb + (yc << 7) + xc;
        uint* trow = (uint*)&tile[tid * 72];
#pragma unroll
        for (int c8 = 0; c8 < 8; ++c8) {
            uint4 d;
            float v0 = valid ? gp[(c8 * 8 + 0) << 14] : 0.f;
            float v1 = valid ? gp[(c8 * 8 + 1) << 14] : 0.f;
            float v2 = valid ? gp[(c8 * 8 + 2) << 14] : 0.f;
            float v3 = valid ? gp[(c8 * 8 + 3) << 14] : 0.f;
            float v4 = valid ? gp[(c8 * 8 + 4) << 14] : 0.f;
            float v5 = valid ? gp[(c8 * 8 + 5) << 14] : 0.f;
            float v6 = valid ? gp[(c8 * 8 + 6) << 14] : 0.f;
            float v7 = valid ? gp[(c8 * 8 + 7) << 14] : 0.f;
            d.x = (uint)f2bf(v0) | ((uint)f2bf(v1) << 16);
            d.y = (uint)f2bf(v2) | ((uint)f2bf(v3) << 16);
            d.z = (uint)f2bf(v4) | ((uint)f2bf(v5) << 16);
            d.w = (uint)f2bf(v6) | ((uint)f2bf(v7) << 16);
            *(uint4*)&trow[c8 * 4] = d;
        }
    }
    __syncthreads();

    int l15 = lane & 15, lq = lane >> 4;
    int p1 = (wv << 4) + l15;          // this lane's A-row pixel
    int plh = p1 >> 3, plw = p1 & 7;

    // ---- stage 1: offset conv via MFMA (M=16/wave, N=32, K=576)
    float4x oacc0 = {0.f, 0.f, 0.f, 0.f}, oacc1 = {0.f, 0.f, 0.f, 0.f};
#pragma unroll
    for (int k2 = 0; k2 < 9; ++k2) {
        int kh = k2 / 3, kw = k2 - kh * 3;
        int pos = (plh + 2 + kh) * 15 + (plw + 2 + kw);
        int abase = pos * 72 + (lq << 3);
#pragma unroll
        for (int half = 0; half < 2; ++half) {
            int kk = k2 * 2 + half;
            short8x a = *(const short8x*)&tile[abase + half * 32];
            short8x b0 = *(const short8x*)&Bo[(kk * 2 + 0) * 512 + (lane << 3)];
            short8x b1 = *(const short8x*)&Bo[(kk * 2 + 1) * 512 + (lane << 3)];
            oacc0 = __builtin_amdgcn_mfma_f32_16x16x32_bf16(a, b0, oacc0, 0, 0, 0);
            oacc1 = __builtin_amdgcn_mfma_f32_16x16x32_bf16(a, b1, oacc1, 0, 0, 0);
        }
    }
    {   // scatter D (col n = lane&15 [+16], row = lq*4+r) + bias -> offl[px][ch]
        int n0 = l15, n1 = 16 + l15;
        float bo0 = boff[n0];
        float bo1 = (n1 < 18) ? boff[n1] : 0.f;
#pragma unroll
        for (int r = 0; r < 4; ++r) {
            int p = (wv << 4) + (lq << 2) + r;
            offl[p * 18 + n0] = oacc0[r] + bo0;
            if (n1 < 18) offl[p * 18 + n1] = oacc1[r] + bo1;
        }
    }
    __syncthreads();

    // ---- stage 2: deformable GEMM
    float4x acc[4];
#pragma unroll
    for (int nt = 0; nt < 4; ++nt) acc[nt] = (float4x){0.f, 0.f, 0.f, 0.f};

#pragma unroll 1
    for (int k2 = 0; k2 < 9; ++k2) {
        int kh = k2 / 3, kw = k2 - kh * 3;
        float2 dd = *(const float2*)&offl[p1 * 18 + k2 * 2];  // dy, dx
        float sy = (float)(plh + 2 + kh) + dd.x;   // tile coords
        float sx = (float)(plw + 2 + kw) + dd.y;
        float yf = floorf(sy), xf = floorf(sx);
        int by = (int)yf, bx = (int)xf;
        float wy1 = sy - yf, wx1 = sx - xf;
        float wy0 = 1.f - wy1, wx0 = 1.f - wx1;
        float w00 = wy0 * wx0, w01 = wy0 * wx1;
        float w10 = wy1 * wx0, w11 = wy1 * wx1;
        bool oob = ((unsigned)by > 13u) | ((unsigned)bx > 13u);
        int byc = min(max(by, 0), 13), bxc = min(max(bx, 0), 13);
        int base = (byc * 15 + bxc) * 72 + (lq << 3);
        bool anyoob = __any(oob);

#pragma unroll
        for (int half = 0; half < 2; ++half) {
            int kk = k2 * 2 + half;
            int cb = base + half * 32;
            short8x c00 = *(const short8x*)&tile[cb];
            short8x c01 = *(const short8x*)&tile[cb + 72];
            short8x c10 = *(const short8x*)&tile[cb + 72 * 15];
            short8x c11 = *(const short8x*)&tile[cb + 72 * 16];
            float s[8];
#pragma unroll
            for (int j = 0; j < 8; ++j) {
                s[j] = w00 * bf2f((ushort)c00[j]) + w01 * bf2f((ushort)c01[j])
                     + w10 * bf2f((ushort)c10[j]) + w11 * bf2f((ushort)c11[j]);
            }
            if (anyoob) {  // exact global fix for |offset|>2 samples (rare)
                int y0g = by + h0 - 3, x0g = bx + w0 - 3;
                int y1g = y0g + 1, x1g = x0g + 1;
                float m00 = ((unsigned)y0g < 128u && (unsigned)x0g < 128u) ? w00 : 0.f;
                float m01 = ((unsigned)y0g < 128u && (unsigned)x1g < 128u) ? w01 : 0.f;
                float m10 = ((unsigned)y1g < 128u && (unsigned)x0g < 128u) ? w10 : 0.f;
                float m11 = ((unsigned)y1g < 128u && (unsigned)x1g < 128u) ? w11 : 0.f;
                int y0c = min(max(y0g, 0), 127), y1c = min(max(y1g, 0), 127);
                int x0c = min(max(x0g, 0), 127), x1c = min(max(x1g, 0), 127);
                int i00 = (y0c << 7) + x0c, i01 = (y0c << 7) + x1c;
                int i10 = (y1c << 7) + x0c, i11 = (y1c << 7) + x1c;
                int cin0 = half * 32 + (lq << 3);
                if (oob) {
#pragma unroll
                    for (int j = 0; j < 8; ++j) {
                        const float* xp = xb + ((long)(cin0 + j) << 14);
                        s[j] = m00 * xp[i00] + m01 * xp[i01]
                             + m10 * xp[i10] + m11 * xp[i11];
                    }
                }
            }
            union { short8x v; ushort u[8]; } A;
#pragma unroll
            for (int j = 0; j < 8; ++j) A.u[j] = f2bf(s[j]);
#pragma unroll
            for (int nt = 0; nt < 4; ++nt) {
                short8x bw = *(const short8x*)&Bd[(kk * 4 + nt) * 512 + (lane << 3)];
                acc[nt] = __builtin_amdgcn_mfma_f32_16x16x32_bf16(A.v, bw, acc[nt], 0, 0, 0);
            }
        }
    }

    // ---- epilogue: transpose D through LDS, coalesced 32B-run stores
    __syncthreads();
    float* ob = (float*)tile;  // [64 px][65] f32 = 16640 B, aliases tile
#pragma unroll
    for (int nt = 0; nt < 4; ++nt) {
        int n = (nt << 4) + l15;
#pragma unroll
        for (int r = 0; r < 4; ++r) {
            int p = (wv << 4) + (lq << 2) + r;
            ob[p * 65 + n] = acc[nt][r];
        }
    }
    __syncthreads();
    {
        int n = tid >> 2, q = tid & 3;
        float bd = bdef[n];
        float* dst = out + (((long)(b * 64 + n)) << 14) + (h0 << 7) + w0;
#pragma unroll
        for (int rr = 0; rr < 2; ++rr) {
            int r = (q << 1) + rr;
            float v[8];
#pragma unroll
            for (int c = 0; c < 8; ++c) v[c] = ob[(r * 8 + c) * 65 + n] + bd;
            float4x s0 = {v[0], v[1], v[2], v[3]};
            float4x s1 = {v[4], v[5], v[6], v[7]};
            *(float4x*)(dst + (r << 7)) = s0;
            *(float4x*)(dst + (r << 7) + 4) = s1;
        }
    }
}

// ---------------------------------------------------------------------------
extern "C" void kernel_launch(void* const* d_in, const int* in_sizes, int n_in,
                              void* d_out, int out_size, void* d_ws, size_t ws_size,
                              hipStream_t stream) {
    const float* x     = (const float*)d_in[0];  // (4,64,128,128)
    const float* w_off = (const float*)d_in[1];  // (18,64,3,3)
    const float* b_off = (const float*)d_in[2];  // (18,)
    const float* w_def = (const float*)d_in[3];  // (64,64,3,3)
    const float* b_def = (const float*)d_in[4];  // (64,)
    float* out = (float*)d_out;                  // (4,64,128,128)

    ushort* Bd = (ushort*)d_ws;                  // 36864 bf16 = 73728 B
    ushort* Bo = Bd + 36864;                     // 18432 bf16 = 36864 B

    hipLaunchKernelGGL(pack_weights, dim3(216), dim3(256), 0, stream,
                       w_def, w_off, Bd, Bo);
    hipLaunchKernelGGL(dcn_fused, dim3(1024), dim3(256), 0, stream,
                       x, Bd, Bo, b_off, b_def, out);
}

// Round 7
// 110.783 us; speedup vs baseline: 4.7478x; 1.0468x over previous
//
#include <hip/hip_runtime.h>

// B=4, CIN=COUT=64, H=W=128, 3x3 deformable conv, fp32 in/out.
// R5 structure (known-good) + R7 deltas ONLY:
//   (1) stage-2 k2 loop fully unrolled (was unroll 1)
//   (2) 9 offset float2s prefetched into registers before the loop
// Everything else byte-identical to R5.

typedef __attribute__((ext_vector_type(8))) short short8x;
typedef __attribute__((ext_vector_type(4))) float float4x;
typedef unsigned short ushort;
typedef unsigned int uint;

__device__ __forceinline__ ushort f2bf(float f) {
    uint b = __float_as_uint(f);
    b += 0x7fffu + ((b >> 16) & 1u);
    return (ushort)(b >> 16);
}
__device__ __forceinline__ float bf2f(ushort u) {
    return __uint_as_float(((uint)u) << 16);
}

// ---------------------------------------------------------------------------
// Prologue: pack weights into MFMA B-fragment order (bf16). (R5 verbatim)
//  Bd [kk(18)][nt(4)][lane(64)][i(8)]: n = nt*16+(lane&15),
//     k = kk*32 + (lane>>4)*8 + i -> k2 = kk>>1, cin = (kk&1)*32+(lane>>4)*8+i
//  Bo [kk(18)][nt(2)][lane][i]: same, n>=18 zero-padded.
// ---------------------------------------------------------------------------
__global__ __launch_bounds__(256) void pack_weights(
    const float* __restrict__ w_def, const float* __restrict__ w_off,
    ushort* __restrict__ Bd, ushort* __restrict__ Bo) {
    int idx = blockIdx.x * 256 + threadIdx.x;
    if (idx < 36864) {
        int i = idx & 7;
        int lane = (idx >> 3) & 63;
        int nt = (idx >> 9) & 3;
        int kk = idx >> 11;
        int n = (nt << 4) + (lane & 15);
        int k2 = kk >> 1;
        int cin = ((kk & 1) << 5) + ((lane >> 4) << 3) + i;
        Bd[idx] = f2bf(w_def[(n * 64 + cin) * 9 + k2]);
    } else if (idx < 36864 + 18432) {
        int d = idx - 36864;
        int i = d & 7;
        int lane = (d >> 3) & 63;
        int nt = (d >> 9) & 1;
        int kk = d >> 10;
        int n = (nt << 4) + (lane & 15);
        int k2 = kk >> 1;
        int cin = ((kk & 1) << 5) + ((lane >> 4) << 3) + i;
        Bo[d] = (n < 18) ? f2bf(w_off[(n * 64 + cin) * 9 + k2]) : (ushort)0;
    }
}

// ---------------------------------------------------------------------------
// Fused kernel. Block = 8x8 pixel tile, 256 threads = 4 waves (M-split:
// wave w owns pixels 16w..16w+15).
// ---------------------------------------------------------------------------
__global__ __launch_bounds__(256, 4) void dcn_fused(
    const float* __restrict__ x, const ushort* __restrict__ Bd,
    const ushort* __restrict__ Bo, const float* __restrict__ boff,
    const float* __restrict__ bdef, float* __restrict__ out) {

    int tid = threadIdx.x;
    int lane = tid & 63, wv = tid >> 6;
    int blk = blockIdx.x;
    int b = blk >> 8, t = blk & 255;
    int h0 = (t >> 4) << 3, w0 = (t & 15) << 3;

    // tile[pos(225, stride 72)][cin(64)+pad8] bf16: 32400 B.
    __shared__ __align__(16) ushort tile[225 * 72];
    __shared__ float offl[64 * 18];  // [px][ch] offsets, 4608 B

    const float* xb = x + ((long)b << 20);

    // ---- stage halo (R5 verbatim): thread = one pos, reads 64 planes.
    if (tid < 225) {
        int ty = tid / 15, tx = tid - ty * 15;
        int y = h0 - 3 + ty, xx = w0 - 3 + tx;
        bool valid = ((unsigned)y < 128u) & ((unsigned)xx < 128u);
        int yc = min(max(y, 0), 127), xc = min(max(xx, 0), 127);
        const float* gp = xb + (yc << 7) + xc;
        uint* trow = (uint*)&tile[tid * 72];
#pragma unroll
        for (int c8 = 0; c8 < 8; ++c8) {
            uint4 d;
            float v0 = valid ? gp[(c8 * 8 + 0) << 14] : 0.f;
            float v1 = valid ? gp[(c8 * 8 + 1) << 14] : 0.f;
            float v2 = valid ? gp[(c8 * 8 + 2) << 14] : 0.f;
            float v3 = valid ? gp[(c8 * 8 + 3) << 14] : 0.f;
            float v4 = valid ? gp[(c8 * 8 + 4) << 14] : 0.f;
            float v5 = valid ? gp[(c8 * 8 + 5) << 14] : 0.f;
            float v6 = valid ? gp[(c8 * 8 + 6) << 14] : 0.f;
            float v7 = valid ? gp[(c8 * 8 + 7) << 14] : 0.f;
            d.x = (uint)f2bf(v0) | ((uint)f2bf(v1) << 16);
            d.y = (uint)f2bf(v2) | ((uint)f2bf(v3) << 16);
            d.z = (uint)f2bf(v4) | ((uint)f2bf(v5) << 16);
            d.w = (uint)f2bf(v6) | ((uint)f2bf(v7) << 16);
            *(uint4*)&trow[c8 * 4] = d;
        }
    }
    __syncthreads();

    int l15 = lane & 15, lq = lane >> 4;
    int p1 = (wv << 4) + l15;          // this lane's A-row pixel
    int plh = p1 >> 3, plw = p1 & 7;

    // ---- stage 1: offset conv via MFMA (R5 verbatim)
    float4x oacc0 = {0.f, 0.f, 0.f, 0.f}, oacc1 = {0.f, 0.f, 0.f, 0.f};
#pragma unroll
    for (int k2 = 0; k2 < 9; ++k2) {
        int kh = k2 / 3, kw = k2 - kh * 3;
        int pos = (plh + 2 + kh) * 15 + (plw + 2 + kw);
        int abase = pos * 72 + (lq << 3);
#pragma unroll
        for (int half = 0; half < 2; ++half) {
            int kk = k2 * 2 + half;
            short8x a = *(const short8x*)&tile[abase + half * 32];
            short8x b0 = *(const short8x*)&Bo[(kk * 2 + 0) * 512 + (lane << 3)];
            short8x b1 = *(const short8x*)&Bo[(kk * 2 + 1) * 512 + (lane << 3)];
            oacc0 = __builtin_amdgcn_mfma_f32_16x16x32_bf16(a, b0, oacc0, 0, 0, 0);
            oacc1 = __builtin_amdgcn_mfma_f32_16x16x32_bf16(a, b1, oacc1, 0, 0, 0);
        }
    }
    {   // scatter D (col n = lane&15 [+16], row = lq*4+r) + bias -> offl[px][ch]
        int n0 = l15, n1 = 16 + l15;
        float bo0 = boff[n0];
        float bo1 = (n1 < 18) ? boff[n1] : 0.f;
#pragma unroll
        for (int r = 0; r < 4; ++r) {
            int p = (wv << 4) + (lq << 2) + r;
            offl[p * 18 + n0] = oacc0[r] + bo0;
            if (n1 < 18) offl[p * 18 + n1] = oacc1[r] + bo1;
        }
    }
    __syncthreads();

    // ---- R7 delta (2): prefetch this pixel's 9 offset pairs to registers
    float2 offr[9];
#pragma unroll
    for (int k2 = 0; k2 < 9; ++k2)
        offr[k2] = *(const float2*)&offl[p1 * 18 + k2 * 2];

    // ---- stage 2: deformable GEMM — R7 delta (1): fully unrolled
    float4x acc[4];
#pragma unroll
    for (int nt = 0; nt < 4; ++nt) acc[nt] = (float4x){0.f, 0.f, 0.f, 0.f};

#pragma unroll
    for (int k2 = 0; k2 < 9; ++k2) {
        const int kh = k2 / 3, kw = k2 - kh * 3;
        float dy = offr[k2].x, dx = offr[k2].y;
        float sy = (float)(plh + 2 + kh) + dy;   // tile coords
        float sx = (float)(plw + 2 + kw) + dx;
        float yf = floorf(sy), xf = floorf(sx);
        int by = (int)yf, bx = (int)xf;
        float wy1 = sy - yf, wx1 = sx - xf;
        float wy0 = 1.f - wy1, wx0 = 1.f - wx1;
        float w00 = wy0 * wx0, w01 = wy0 * wx1;
        float w10 = wy1 * wx0, w11 = wy1 * wx1;
        bool oob = ((unsigned)by > 13u) | ((unsigned)bx > 13u);
        int byc = min(max(by, 0), 13), bxc = min(max(bx, 0), 13);
        int base = (byc * 15 + bxc) * 72 + (lq << 3);
        bool anyoob = __any(oob);

#pragma unroll
        for (int half = 0; half < 2; ++half) {
            int kk = k2 * 2 + half;
            int cb = base + half * 32;
            short8x c00 = *(const short8x*)&tile[cb];
            short8x c01 = *(const short8x*)&tile[cb + 72];
            short8x c10 = *(const short8x*)&tile[cb + 72 * 15];
            short8x c11 = *(const short8x*)&tile[cb + 72 * 16];
            float s[8];
#pragma unroll
            for (int j = 0; j < 8; ++j) {
                s[j] = w00 * bf2f((ushort)c00[j]) + w01 * bf2f((ushort)c01[j])
                     + w10 * bf2f((ushort)c10[j]) + w11 * bf2f((ushort)c11[j]);
            }
            if (anyoob) {  // exact global fix for |offset|>2 samples (rare)
                int y0g = by + h0 - 3, x0g = bx + w0 - 3;
                int y1g = y0g + 1, x1g = x0g + 1;
                float m00 = ((unsigned)y0g < 128u && (unsigned)x0g < 128u) ? w00 : 0.f;
                float m01 = ((unsigned)y0g < 128u && (unsigned)x1g < 128u) ? w01 : 0.f;
                float m10 = ((unsigned)y1g < 128u && (unsigned)x0g < 128u) ? w10 : 0.f;
                float m11 = ((unsigned)y1g < 128u && (unsigned)x1g < 128u) ? w11 : 0.f;
                int y0c = min(max(y0g, 0), 127), y1c = min(max(y1g, 0), 127);
                int x0c = min(max(x0g, 0), 127), x1c = min(max(x1g, 0), 127);
                int i00 = (y0c << 7) + x0c, i01 = (y0c << 7) + x1c;
                int i10 = (y1c << 7) + x0c, i11 = (y1c << 7) + x1c;
                int cin0 = half * 32 + (lq << 3);
                if (oob) {
#pragma unroll
                    for (int j = 0; j < 8; ++j) {
                        const float* xp = xb + ((long)(cin0 + j) << 14);
                        s[j] = m00 * xp[i00] + m01 * xp[i01]
                             + m10 * xp[i10] + m11 * xp[i11];
                    }
                }
            }
            union { short8x v; ushort u[8]; } A;
#pragma unroll
            for (int j = 0; j < 8; ++j) A.u[j] = f2bf(s[j]);
#pragma unroll
            for (int nt = 0; nt < 4; ++nt) {
                short8x bw = *(const short8x*)&Bd[(kk * 4 + nt) * 512 + (lane << 3)];
                acc[nt] = __builtin_amdgcn_mfma_f32_16x16x32_bf16(A.v, bw, acc[nt], 0, 0, 0);
            }
        }
    }

    // ---- epilogue (R5 verbatim): transpose D through LDS, coalesced stores
    __syncthreads();
    float* ob = (float*)tile;  // [64 px][65] f32 = 16640 B, aliases tile
#pragma unroll
    for (int nt = 0; nt < 4; ++nt) {
        int n = (nt << 4) + l15;
#pragma unroll
        for (int r = 0; r < 4; ++r) {
            int p = (wv << 4) + (lq << 2) + r;
            ob[p * 65 + n] = acc[nt][r];
        }
    }
    __syncthreads();
    {
        int n = tid >> 2, q = tid & 3;
        float bd = bdef[n];
        float* dst = out + (((long)(b * 64 + n)) << 14) + (h0 << 7) + w0;
#pragma unroll
        for (int rr = 0; rr < 2; ++rr) {
            int r = (q << 1) + rr;
            float v[8];
#pragma unroll
            for (int c = 0; c < 8; ++c) v[c] = ob[(r * 8 + c) * 65 + n] + bd;
            float4x s0 = {v[0], v[1], v[2], v[3]};
            float4x s1 = {v[4], v[5], v[6], v[7]};
            *(float4x*)(dst + (r << 7)) = s0;
            *(float4x*)(dst + (r << 7) + 4) = s1;
        }
    }
}

// ---------------------------------------------------------------------------
extern "C" void kernel_launch(void* const* d_in, const int* in_sizes, int n_in,
                              void* d_out, int out_size, void* d_ws, size_t ws_size,
                              hipStream_t stream) {
    const float* x     = (const float*)d_in[0];  // (4,64,128,128)
    const float* w_off = (const float*)d_in[1];  // (18,64,3,3)
    const float* b_off = (const float*)d_in[2];  // (18,)
    const float* w_def = (const float*)d_in[3];  // (64,64,3,3)
    const float* b_def = (const float*)d_in[4];  // (64,)
    float* out = (float*)d_out;                  // (4,64,128,128)

    ushort* Bd = (ushort*)d_ws;                  // 36864 bf16 = 73728 B
    ushort* Bo = Bd + 36864;                     // 18432 bf16 = 36864 B

    hipLaunchKernelGGL(pack_weights, dim3(216), dim3(256), 0, stream,
                       w_def, w_off, Bd, Bo);
    hipLaunchKernelGGL(dcn_fused, dim3(1024), dim3(256), 0, stream,
                       x, Bd, Bo, b_off, b_def, out);
}